// Round 3
// baseline (601.963 us; speedup 1.0000x reference)
//
#include <hip/hip_runtime.h>

// VQ-VAE vector-quantize, fused: distances + argmin + gather + loss.
// x: [65536, 256] fp32, dict: [256, 1024] fp32.
// out: q_ste [65536*256] fp32, then loss scalar at out[65536*256].
//
// NUMERICS (bit-exact vs np reference, verified absmax 0.0 R2-R7 — DO NOT CHANGE):
//  - row norm ||f||^2: np pairwise tree (two 128-halves, 8 accumulators r8[e&7],
//    unfused squares, fixed combine tree; 0+sq == sq so zero-init is exact)
//  - enorm ||e||^2: sequential d ascending, unfused square then plain add
//  - dist = fl( fl(A + B) - 2*s ), argmin first-index on exact ties
//  - STE out = fl(x + fl(q - x)); loss on pure q, (1+BETA)/(N*D) scale
//
// PERF (R7 -> R8):
//  - vq_main: 512 threads/block (8 waves), same BM=128 tile & LDS -> 4 waves/SIMD
//    (was 2). Per-thread tile acc[4][16] (row = 4*ty+r). Same one-barrier-per-step
//    pipeline; the extra wave interleave hides x-load latency + barrier drain.
//  - vq_prep + vq_rnorm merged into vq_aux (one dispatch, one less launch gap):
//    prep transposes dict via LDS (coalesced dictT writes, 256B granules vs 4B
//    @1KB stride); rnorm stages x via LDS (coalesced loads, pitch-17 reads).
//    All summation chains textually preserved.

#define NROWS 65536
#define DDIM  256
#define KC    1024
#define BM    128            // rows per block
#define BC    256            // codes per ct tile
#define DC    16             // d-chunk per pipeline step
#define NDC   16             // DDIM/DC
#define NCT   4              // KC/BC
#define NSTEP 64             // NCT*NDC
#define FXW   160            // 32 row-groups * pitch 5 (160%32==0 -> clean banks)

#define GLOAD_LDS16(gp, lp) __builtin_amdgcn_global_load_lds( \
    (const __attribute__((address_space(1))) void*)(gp),      \
    (__attribute__((address_space(3))) void*)(lp), 16, 0, 0)

// x chunk [128 rows][16 d] -> LDS transposed [d][row-group*5+r]. 1 float4/thread
// (512 threads), regs die immediately (stores right after the vmcnt wait).
#define STAGE_FX(dstbuf, dc_) do {                                              \
    const int r0_ = tid >> 2, c0_ = tid & 3;                                    \
    const float4 v0_ = *(const float4*)&x[(size_t)(rowbase + r0_) * DDIM + (dc_) * DC + c0_ * 4]; \
    float* b0_ = (dstbuf) + (c0_ * 4) * FXW + (r0_ >> 2) * 5 + (r0_ & 3);       \
    b0_[0 * FXW] = v0_.x; b0_[1 * FXW] = v0_.y;                                 \
    b0_[2 * FXW] = v0_.z; b0_[3 * FXW] = v0_.w;                                 \
} while (0)

// dict tile [16 d][256 codes] via async DMA: lds dest = uniform + lane*16.
#define STAGE_DICT(pbuf, ct_, dc_) do {                                         \
    _Pragma("unroll")                                                           \
    for (int i_ = 0; i_ < 2; ++i_) {                                            \
        int flat_ = i_ * 512 + tid;                                             \
        int dd_ = flat_ >> 6;            /* wave-uniform */                     \
        int l4_ = (flat_ & 63) * 4;      /* lane*4 floats = lane*16 B */        \
        GLOAD_LDS16(&dict[(size_t)((dc_) * DC + dd_) * KC + (ct_) * BC + l4_],  \
                    (pbuf) + dd_ * BC + l4_);                                   \
    }                                                                           \
} while (0)

// Merged pre-pass. Blocks 0..3: codebook transpose + column norms (np order:
// rounded square then plain add, d strictly ascending) + loss zero-init.
// Blocks 4..259: row norms ||f||^2 (np pairwise chain r8[e&7], half-combine
// at e=127/255) with LDS-staged coalesced x reads.
__global__ __launch_bounds__(256) void vq_aux(const float* __restrict__ x,
                                              const float* __restrict__ dict,
                                              float* __restrict__ enorm,
                                              float* __restrict__ dictT,
                                              float* __restrict__ rnorm,
                                              float* __restrict__ loss) {
#pragma clang fp contract(off)
    __shared__ float tile[64 * 257];     // prep: [64 d][256 k]+pad; rnorm uses prefix
    const int tid = threadIdx.x;

    if (blockIdx.x < 4) {
        // ---- prep: 256 codebook columns
        const int kb = blockIdx.x * 256;
        if (blockIdx.x == 0 && tid == 0) *loss = 0.f;   // before vq_main (stream order)
        float s = 0.f;
        for (int dc = 0; dc < 4; ++dc) {
            #pragma unroll 8
            for (int dd = 0; dd < 64; ++dd) {           // d = dc*64+dd ascending
                float v = dict[(size_t)(dc * 64 + dd) * KC + kb + tid];  // coalesced
                float sq = v * v;        // rounded square (np temp array)
                s = s + sq;              // plain add, NOT fma (sequential chain)
                tile[dd * 257 + tid] = v;
            }
            __syncthreads();
            // write dictT in 256B granules: 4 threads per k-row, 64 rows/pass
            const int kl = tid >> 2, pc = tid & 3;
            for (int pass = 0; pass < 4; ++pass) {
                int k = pass * 64 + kl;
                #pragma unroll
                for (int j = 0; j < 4; ++j) {
                    int d0 = pc * 16 + j * 4;
                    float4 wv;
                    wv.x = tile[(d0 + 0) * 257 + k];
                    wv.y = tile[(d0 + 1) * 257 + k];
                    wv.z = tile[(d0 + 2) * 257 + k];
                    wv.w = tile[(d0 + 3) * 257 + k];
                    *(float4*)&dictT[(size_t)(kb + k) * DDIM + dc * 64 + d0] = wv;
                }
            }
            __syncthreads();
        }
        enorm[kb + tid] = s;
    } else {
        // ---- rnorm: 256 rows, LDS-staged ([row][16]+pad, pitch 17)
        const int rb = (blockIdx.x - 4) * 256;
        float r8[8] = {0.f, 0.f, 0.f, 0.f, 0.f, 0.f, 0.f, 0.f};
        float halfv0 = 0.f;
        for (int c = 0; c < NDC; ++c) {
            __syncthreads();             // protect previous chunk's reads
            #pragma unroll
            for (int i = 0; i < 4; ++i) {
                int flat = i * 256 + tid;            // 0..1023
                int rl = flat >> 2, c4 = flat & 3;
                float4 v = *(const float4*)&x[(size_t)(rb + rl) * DDIM + c * 16 + c4 * 4];
                tile[rl * 17 + c4 * 4 + 0] = v.x;
                tile[rl * 17 + c4 * 4 + 1] = v.y;
                tile[rl * 17 + c4 * 4 + 2] = v.z;
                tile[rl * 17 + c4 * 4 + 3] = v.w;
            }
            __syncthreads();
            #pragma unroll
            for (int dd = 0; dd < 16; ++dd) {        // e = c*16+dd; e&7 == dd&7
                float v = tile[tid * 17 + dd];
                float sq = v * v;
                r8[dd & 7] = r8[dd & 7] + sq;
            }
            if (c == 7) {                            // half boundary at elem 128
                halfv0 = ((r8[0] + r8[1]) + (r8[2] + r8[3]))
                       + ((r8[4] + r8[5]) + (r8[6] + r8[7]));
                #pragma unroll
                for (int j = 0; j < 8; ++j) r8[j] = 0.f;
            }
        }
        float h1 = ((r8[0] + r8[1]) + (r8[2] + r8[3]))
                 + ((r8[4] + r8[5]) + (r8[6] + r8[7]));
        rnorm[rb + tid] = halfv0 + h1;
    }
}

__global__ __launch_bounds__(512, 4) void vq_main(const float* __restrict__ x,
                                                  const float* __restrict__ dict,
                                                  const float* __restrict__ enorm,
                                                  const float* __restrict__ dictT,
                                                  const float* __restrict__ rnorm,
                                                  float* __restrict__ out,
                                                  float* __restrict__ loss) {
    __shared__ float fXb[2][DC * FXW];   // 10 KB each
    __shared__ float dTs[2][DC * BC];    // 16 KB each  -> 52 KB, 2 blk/CU (8 waves ea)

    const int tid = threadIdx.x;         // 0..511
    const int tx  = tid & 15;            // 16 code-groups x 16 codes = 256
    const int ty  = tid >> 4;            // 32 row-groups  x  4 rows  = 128
    const int rowbase = blockIdx.x * BM;

    // Row norms from vq_aux (broadcast loads: 16 lanes share ty). row = 4*ty+r.
    float Arow[4];
    #pragma unroll
    for (int r = 0; r < 4; ++r) Arow[r] = rnorm[rowbase + ty * 4 + r];

    float minv[4];
    int   mini[4];
    #pragma unroll
    for (int r = 0; r < 4; ++r) { minv[r] = 3.4e38f; mini[r] = 0; }

    // ---- Prologue: dict tile (0,0) DMA + x chunk 0, one barrier drains both.
    STAGE_DICT(&dTs[0][0], 0, 0);
    STAGE_FX(&fXb[0][0], 0);
    __syncthreads();

    float acc[4][16];
    // ---- Main: 64 steps, one barrier each.
    #pragma unroll 2                     // compile-time buffer parity
    for (int s = 0; s < NSTEP; ++s) {
        const int p = s & 1;
        if (s < NSTEP - 1) {
            const int ns = s + 1;
            STAGE_DICT(&dTs[1 - p][0], ns >> 4, ns & 15);  // async, 0 regs
            STAGE_FX(&fXb[1 - p][0], ns & 15);             // regs die here
        }
        if ((s & 15) == 0) {
            #pragma unroll
            for (int r = 0; r < 4; ++r)
                #pragma unroll
                for (int j = 0; j < 16; ++j) acc[r][j] = 0.f;
        }
        #pragma unroll 4
        for (int dd = 0; dd < DC; ++dd) {
            // rows 4*ty..4*ty+3 live at group ty, slots 0..3 (one float4)
            const float4 f0 = *(const float4*)&fXb[p][dd * FXW + ty * 5];
            const float4 e0 = *(const float4*)&dTs[p][dd * BC + tx * 4];
            const float4 e1 = *(const float4*)&dTs[p][dd * BC + 64 + tx * 4];
            const float4 e2 = *(const float4*)&dTs[p][dd * BC + 128 + tx * 4];
            const float4 e3 = *(const float4*)&dTs[p][dd * BC + 192 + tx * 4];
            const float fr[4]  = {f0.x, f0.y, f0.z, f0.w};
            const float ec[16] = {e0.x, e0.y, e0.z, e0.w, e1.x, e1.y, e1.z, e1.w,
                                  e2.x, e2.y, e2.z, e2.w, e3.x, e3.y, e3.z, e3.w};
            #pragma unroll
            for (int r = 0; r < 4; ++r)
                #pragma unroll
                for (int j = 0; j < 16; ++j)
                    acc[r][j] = fmaf(fr[r], ec[j], acc[r][j]);
        }
        if ((s & 15) == 15) {
            // dist = fl( fl(A + B) - 2*s ) — np rounding chain (fma of
            // t1 - 2*acc bit-identical: 2*acc exact). Codes ascend with
            // (ct, j) for fixed tx -> strict < keeps FIRST min index.
            const int cbase = (s >> 4) * BC;
            float en[16];
            #pragma unroll
            for (int j = 0; j < 16; ++j)
                en[j] = enorm[cbase + (j >> 2) * 64 + tx * 4 + (j & 3)];
            #pragma unroll
            for (int r = 0; r < 4; ++r)
                #pragma unroll
                for (int j = 0; j < 16; ++j) {
                    int code = cbase + (j >> 2) * 64 + tx * 4 + (j & 3);
                    float t1 = Arow[r] + en[j];
                    float dist = t1 - 2.0f * acc[r][j];
                    if (dist < minv[r]) { minv[r] = dist; mini[r] = code; }
                }
        }
        __syncthreads();
    }

    // Cross-lane argmin over the 16 tx lanes (xor<16 stays in-wave; lane =
    // (ty&3)*16 + tx). Tie -> smaller index (first occurrence).
    #pragma unroll
    for (int m = 1; m < 16; m <<= 1)
        #pragma unroll
        for (int r = 0; r < 4; ++r) {
            float ov = __shfl_xor(minv[r], m, 64);
            int   oi = __shfl_xor(mini[r], m, 64);
            if (ov < minv[r] || (ov == minv[r] && oi < mini[r])) {
                minv[r] = ov; mini[r] = oi;
            }
        }

    int* idx_s = (int*)&dTs[0][0];       // loop-end barrier covers last compute
    if (tx == 0) {
        #pragma unroll
        for (int r = 0; r < 4; ++r) idx_s[ty * 4 + r] = mini[r];
    }
    __syncthreads();

    // Epilogue: gather codebook row (dictT L2-resident), re-read x (L3-hot),
    // emulate STE out = fl(x + fl(q-x)), loss on pure q (before STE).
    // 512 threads: col = tid&255, row-half = tid>>8 (64 rows each).
    // lsum chain per thread stays sequential; nontemporal stores (no L2 RFO).
    float lsum = 0.f;
    {
#pragma clang fp contract(off)
        const int ecol = tid & 255;
        const int erh  = tid >> 8;
        #pragma unroll 2
        for (int i = 0; i < 64; ++i) {
            int row = erh * 64 + i;
            int k = idx_s[row];
            float qv = dictT[(size_t)k * DDIM + ecol];
            float xv = x[(size_t)(rowbase + row) * DDIM + ecol];
            float diff = qv - xv;                                 // fl(q - x)
            __builtin_nontemporal_store(xv + diff,
                &out[(size_t)(rowbase + row) * DDIM + ecol]);     // fl(x + fl(q-x))
            float d = xv - qv;
            float dsq = d * d;
            lsum = lsum + dsq;
        }
    }
    #pragma unroll
    for (int off = 32; off > 0; off >>= 1)
        lsum += __shfl_down(lsum, off, 64);
    if ((tid & 63) == 0)
        atomicAdd(loss, lsum * (1.25f / 16777216.0f));  // (1+BETA)/(N*D)
}

extern "C" void kernel_launch(void* const* d_in, const int* in_sizes, int n_in,
                              void* d_out, int out_size, void* d_ws, size_t ws_size,
                              hipStream_t stream) {
    (void)in_sizes; (void)n_in; (void)out_size; (void)ws_size;
    const float* x    = (const float*)d_in[0];
    const float* dict = (const float*)d_in[1];
    float* out   = (float*)d_out;
    float* enorm = (float*)d_ws;                 // 1024 floats
    float* dictT = enorm + KC;                   // 1024*256 floats (1 MB)
    float* rnorm = dictT + (size_t)KC * DDIM;    // 65536 floats (256 KB)
    float* loss  = out + (size_t)NROWS * DDIM;   // scalar slot after q

    vq_aux<<<4 + NROWS / 256, 256, 0, stream>>>(x, dict, enorm, dictT, rnorm, loss);
    vq_main<<<NROWS / BM, 512, 0, stream>>>(x, dict, enorm, dictT, rnorm, out, loss);
}

// Round 4
// 529.074 us; speedup vs baseline: 1.1378x; 1.1378x over previous
//
#include <hip/hip_runtime.h>

// VQ-VAE vector-quantize, fused: distances + argmin + gather + loss.
// x: [65536, 256] fp32, dict: [256, 1024] fp32.
// out: q_ste [65536*256] fp32, then loss scalar at out[65536*256].
//
// NUMERICS (bit-exact vs np reference, verified absmax 0.0 R2-R8 — DO NOT CHANGE):
//  - row norm ||f||^2: np pairwise tree (two INDEPENDENT 128-halves, each an
//    8-accumulator r8[e&7] chain, unfused squares, fixed combine tree,
//    result = half0_tree + half1_tree; 0+sq == sq so zero-init is exact)
//  - enorm ||e||^2: sequential d ascending, unfused square then plain add
//  - dist = fl( fl(A + B) - 2*s ), argmin first-index on exact ties
//  - STE out = fl(x + fl(q - x)); loss on pure q, (1+BETA)/(N*D) scale
//
// PERF (R8 -> R9): R8's 512-thread main REGRESSED (acc[4][16] halves FMA
// density; VALU work +12%). Revert to R7's 256-thread acc[8][16] loop, then:
//  - FXW 160 -> 128 (drop pitch-5 padding): f-reads stay conflict-free
//    (4 ty-groups -> banks {0,8,16,24}, 16-way broadcast free), write
//    conflicts unchanged. LDS 52 -> 48 KB => 3 blocks/CU (was 2).
//  - vq_rnorm: 2 threads/row (independent 128-halves of the np chain),
//    __shfl_down combine. 2x waves for the latency-bound norm pass.

#define NROWS 65536
#define DDIM  256
#define KC    1024
#define BM    128            // rows per block
#define BC    256            // codes per ct tile
#define DC    16             // d-chunk per pipeline step
#define NDC   16             // DDIM/DC
#define NCT   4              // KC/BC
#define NSTEP 64             // NCT*NDC
#define FXW   128            // 128 rows, pitch 4 packed (no pad; reads conflict-free)

#define GLOAD_LDS16(gp, lp) __builtin_amdgcn_global_load_lds( \
    (const __attribute__((address_space(1))) void*)(gp),      \
    (__attribute__((address_space(3))) void*)(lp), 16, 0, 0)

// x chunk [128 rows][16 d] -> LDS transposed [d][row]. 2 float4/thread,
// regs die immediately (stores right after the vmcnt wait).
#define STAGE_FX(dstbuf, dc_) do {                                              \
    const int r0_ = tid >> 2, c0_ = tid & 3;                                    \
    const float4 v0_ = *(const float4*)&x[(size_t)(rowbase + r0_) * DDIM + (dc_) * DC + c0_ * 4];      \
    const float4 v1_ = *(const float4*)&x[(size_t)(rowbase + 64 + r0_) * DDIM + (dc_) * DC + c0_ * 4]; \
    float* b0_ = (dstbuf) + (c0_ * 4) * FXW + r0_;                              \
    b0_[0 * FXW] = v0_.x; b0_[1 * FXW] = v0_.y;                                 \
    b0_[2 * FXW] = v0_.z; b0_[3 * FXW] = v0_.w;                                 \
    float* b1_ = b0_ + 64;               /* +64 rows */                         \
    b1_[0 * FXW] = v1_.x; b1_[1 * FXW] = v1_.y;                                 \
    b1_[2 * FXW] = v1_.z; b1_[3 * FXW] = v1_.w;                                 \
} while (0)

// dict tile [16 d][256 codes] via async DMA: lds dest = uniform + lane*16.
#define STAGE_DICT(pbuf, ct_, dc_) do {                                         \
    _Pragma("unroll")                                                           \
    for (int i_ = 0; i_ < 4; ++i_) {                                            \
        int flat_ = i_ * 256 + tid;                                             \
        int dd_ = flat_ >> 6;            /* wave-uniform */                     \
        int l4_ = (flat_ & 63) * 4;      /* lane*4 floats = lane*16 B */        \
        GLOAD_LDS16(&dict[(size_t)((dc_) * DC + dd_) * KC + (ct_) * BC + l4_],  \
                    (pbuf) + dd_ * BC + l4_);                                   \
    }                                                                           \
} while (0)

// Pre-kernel: codebook column norms (np order: rounded square then plain add,
// sequential d ascending) + transposed codebook + loss zero-init.
__global__ __launch_bounds__(256) void vq_prep(const float* __restrict__ dict,
                                               float* __restrict__ enorm,
                                               float* __restrict__ dictT,
                                               float* __restrict__ loss) {
#pragma clang fp contract(off)
    int k = blockIdx.x * 256 + threadIdx.x;
    if (k == 0) *loss = 0.f;   // runs before vq_main (stream order)
    float s = 0.f;
    #pragma unroll 8
    for (int d = 0; d < DDIM; ++d) {
        float v = dict[(size_t)d * KC + k];
        float sq = v * v;          // rounded square (np temp array)
        s = s + sq;                // plain add, NOT fma (chain stays sequential)
        dictT[(size_t)k * DDIM + d] = v;
    }
    enorm[k] = s;
}

// Row norms ||f||^2, TWO threads per row (the np chain's 128-halves are
// independent sub-chains combined as half0 + half1). Each thread: 8
// accumulators indexed (local e)&7, elements ascending, fixed combine tree —
// textually the verified chain. Even lane holds half 0, odd half 1;
// __shfl_down(1) pairs them. L1 absorbs the 1 KB lane stride (each 64B line
// feeds 4 consecutive float4 iters of the same thread).
__global__ __launch_bounds__(256) void vq_rnorm(const float* __restrict__ x,
                                                float* __restrict__ rnorm) {
#pragma clang fp contract(off)
    int gt   = blockIdx.x * 256 + threadIdx.x;   // 2*NROWS threads
    int row  = gt >> 1;
    int half = gt & 1;
    const float* xr = x + (size_t)row * DDIM + half * 128;
    float r8[8] = {0.f, 0.f, 0.f, 0.f, 0.f, 0.f, 0.f, 0.f};
    #pragma unroll 8
    for (int c = 0; c < 32; ++c) {       // local e = 4c..4c+3 ; e&7 == (c&1)*4+k
        float4 v = *(const float4*)&xr[c * 4];
        int b = (c & 1) * 4;
        float s0 = v.x * v.x; r8[b + 0] = r8[b + 0] + s0;
        float s1 = v.y * v.y; r8[b + 1] = r8[b + 1] + s1;
        float s2 = v.z * v.z; r8[b + 2] = r8[b + 2] + s2;
        float s3 = v.w * v.w; r8[b + 3] = r8[b + 3] + s3;
    }
    float h = ((r8[0] + r8[1]) + (r8[2] + r8[3]))
            + ((r8[4] + r8[5]) + (r8[6] + r8[7]));
    float ho = __shfl_down(h, 1, 64);    // odd lane's half-1 tree
    if (half == 0) rnorm[row] = h + ho;  // fl(half0 + half1) — verified chain
}

__global__ __launch_bounds__(256, 2) void vq_main(const float* __restrict__ x,
                                                  const float* __restrict__ dict,
                                                  const float* __restrict__ enorm,
                                                  const float* __restrict__ dictT,
                                                  const float* __restrict__ rnorm,
                                                  float* __restrict__ out,
                                                  float* __restrict__ loss) {
    __shared__ float fXb[2][DC * FXW];   // 8 KB each
    __shared__ float dTs[2][DC * BC];    // 16 KB each  -> total 48 KB, 3 blk/CU

    const int tid = threadIdx.x;
    const int tx  = tid & 15;            // 16 code-groups x 16 codes = 256
    const int ty  = tid >> 4;            // 16 row-groups  x  8 rows  = 128
    const int rowbase = blockIdx.x * BM;

    // Row norms from vq_rnorm (broadcast loads: 16 lanes share ty). row = 8*ty+r.
    float Arow[8];
    #pragma unroll
    for (int r = 0; r < 8; ++r) Arow[r] = rnorm[rowbase + ty * 8 + r];

    float minv[8];
    int   mini[8];
    #pragma unroll
    for (int r = 0; r < 8; ++r) { minv[r] = 3.4e38f; mini[r] = 0; }

    // ---- Prologue: dict tile (0,0) DMA + x chunk 0, one barrier drains both.
    STAGE_DICT(&dTs[0][0], 0, 0);
    STAGE_FX(&fXb[0][0], 0);
    __syncthreads();

    float acc[8][16];
    // ---- Main: 64 steps, one barrier each.
    #pragma unroll 2                     // compile-time buffer parity
    for (int s = 0; s < NSTEP; ++s) {
        const int p = s & 1;
        if (s < NSTEP - 1) {
            const int ns = s + 1;
            STAGE_DICT(&dTs[1 - p][0], ns >> 4, ns & 15);  // async, 0 regs
            STAGE_FX(&fXb[1 - p][0], ns & 15);             // regs die here
        }
        if ((s & 15) == 0) {
            #pragma unroll
            for (int r = 0; r < 8; ++r)
                #pragma unroll
                for (int j = 0; j < 16; ++j) acc[r][j] = 0.f;
        }
        #pragma unroll 4
        for (int dd = 0; dd < DC; ++dd) {
            // rows 8*ty..8*ty+7 at [dd][ty*8 .. ty*8+7] (pitch-4 packed)
            const float4 f0 = *(const float4*)&fXb[p][dd * FXW + ty * 8];
            const float4 f1 = *(const float4*)&fXb[p][dd * FXW + ty * 8 + 4];
            const float4 e0 = *(const float4*)&dTs[p][dd * BC + tx * 4];
            const float4 e1 = *(const float4*)&dTs[p][dd * BC + 64 + tx * 4];
            const float4 e2 = *(const float4*)&dTs[p][dd * BC + 128 + tx * 4];
            const float4 e3 = *(const float4*)&dTs[p][dd * BC + 192 + tx * 4];
            const float fr[8]  = {f0.x, f0.y, f0.z, f0.w, f1.x, f1.y, f1.z, f1.w};
            const float ec[16] = {e0.x, e0.y, e0.z, e0.w, e1.x, e1.y, e1.z, e1.w,
                                  e2.x, e2.y, e2.z, e2.w, e3.x, e3.y, e3.z, e3.w};
            #pragma unroll
            for (int r = 0; r < 8; ++r)
                #pragma unroll
                for (int j = 0; j < 16; ++j)
                    acc[r][j] = fmaf(fr[r], ec[j], acc[r][j]);
        }
        if ((s & 15) == 15) {
            // dist = fl( fl(A + B) - 2*s ) — np rounding chain (fma of
            // t1 - 2*acc bit-identical: 2*acc exact). Codes ascend with
            // (ct, j) for fixed tx -> strict < keeps FIRST min index.
            const int cbase = (s >> 4) * BC;
            float en[16];
            #pragma unroll
            for (int j = 0; j < 16; ++j)
                en[j] = enorm[cbase + (j >> 2) * 64 + tx * 4 + (j & 3)];
            #pragma unroll
            for (int r = 0; r < 8; ++r)
                #pragma unroll
                for (int j = 0; j < 16; ++j) {
                    int code = cbase + (j >> 2) * 64 + tx * 4 + (j & 3);
                    float t1 = Arow[r] + en[j];
                    float dist = t1 - 2.0f * acc[r][j];
                    if (dist < minv[r]) { minv[r] = dist; mini[r] = code; }
                }
        }
        __syncthreads();
    }

    // Cross-lane argmin over the 16 tx lanes (xor<16 stays in-wave; lane =
    // (ty&3)*16 + tx). Tie -> smaller index (first occurrence).
    #pragma unroll
    for (int m = 1; m < 16; m <<= 1)
        #pragma unroll
        for (int r = 0; r < 8; ++r) {
            float ov = __shfl_xor(minv[r], m, 64);
            int   oi = __shfl_xor(mini[r], m, 64);
            if (ov < minv[r] || (ov == minv[r] && oi < mini[r])) {
                minv[r] = ov; mini[r] = oi;
            }
        }

    int* idx_s = (int*)&dTs[0][0];       // loop-end barrier covers last compute
    if (tx == 0) {
        #pragma unroll
        for (int r = 0; r < 8; ++r) idx_s[ty * 8 + r] = mini[r];
    }
    __syncthreads();

    // Epilogue: gather codebook row (dictT L2-resident), re-read x (L3-hot),
    // emulate STE out = fl(x + fl(q-x)), loss on pure q (before STE).
    // unroll 2 = load ILP; lsum chain order preserved (no reassociation).
    // Nontemporal store: out is write-only, skip L2 RFO.
    float lsum = 0.f;
    {
#pragma clang fp contract(off)
        #pragma unroll 2
        for (int i = 0; i < BM; ++i) {
            int k = idx_s[i];
            float qv = dictT[(size_t)k * DDIM + tid];
            float xv = x[(size_t)(rowbase + i) * DDIM + tid];
            float diff = qv - xv;                                 // fl(q - x)
            __builtin_nontemporal_store(xv + diff,
                &out[(size_t)(rowbase + i) * DDIM + tid]);        // fl(x + fl(q-x))
            float d = xv - qv;
            float dsq = d * d;
            lsum = lsum + dsq;
        }
    }
    #pragma unroll
    for (int off = 32; off > 0; off >>= 1)
        lsum += __shfl_down(lsum, off, 64);
    if ((tid & 63) == 0)
        atomicAdd(loss, lsum * (1.25f / 16777216.0f));  // (1+BETA)/(N*D)
}

extern "C" void kernel_launch(void* const* d_in, const int* in_sizes, int n_in,
                              void* d_out, int out_size, void* d_ws, size_t ws_size,
                              hipStream_t stream) {
    (void)in_sizes; (void)n_in; (void)out_size; (void)ws_size;
    const float* x    = (const float*)d_in[0];
    const float* dict = (const float*)d_in[1];
    float* out   = (float*)d_out;
    float* enorm = (float*)d_ws;                 // 1024 floats
    float* dictT = enorm + KC;                   // 1024*256 floats (1 MB)
    float* rnorm = dictT + (size_t)KC * DDIM;    // 65536 floats (256 KB)
    float* loss  = out + (size_t)NROWS * DDIM;   // scalar slot after q

    vq_prep<<<KC / 256, 256, 0, stream>>>(dict, enorm, dictT, loss);
    vq_rnorm<<<2 * NROWS / 256, 256, 0, stream>>>(x, rnorm);
    vq_main<<<NROWS / BM, 256, 0, stream>>>(x, dict, enorm, dictT, rnorm, out, loss);
}